// Round 9
// baseline (1007.958 us; speedup 1.0000x reference)
//
#include <hip/hip_runtime.h>
#include <hip/hip_bf16.h>

#define B_ 32
#define P_ 512
#define Q_ 64
#define E_ 300
#define KP 320          // E padded to multiple of 32 for MFMA K-steps
#define H_ 256
#define HH_ 128
#define NEG (-1e7f)
#define BP (B_*P_)
#define BQ (B_*Q_)

typedef __attribute__((ext_vector_type(8))) short bf16x8;
typedef __attribute__((ext_vector_type(4))) float f32x4;

// ---- static device workspace (fully rewritten every call) ----
// Embeddings gathered T-MAJOR: row = t*32 + b
__device__ __hip_bfloat16 g_ep[BP][KP];
__device__ __hip_bfloat16 g_eq[BQ][KP];
__device__ __hip_bfloat16 g_wp[768][KP];     // combined passage wih
__device__ __hip_bfloat16 g_wq[768][KP];     // combined question wih
__device__ float g_biasp[768];               // bih (+ bhh for r,z gates)
__device__ float g_biasq[768];
__device__ float g_biasn[4][HH_];            // bhh n-gate bias per weight set
__device__ short g_whhrep[4*12*512*8];       // whh repacked in MFMA B-frag order
// x projections as bf16 tiles: [dir][t][g=chain-group][col 0..383][chain 0..15]
__device__ short g_xtp[2L*P_*2*384*16];
__device__ short g_xtq[2L*Q_*2*384*16];
__device__ float g_penc[BP*H_];              // BiGRU passage encodings (f32)
__device__ float g_qenc[BQ*H_];              // BiGRU question encodings

struct PrepArgs { const float* wih[4]; const float* bih[4]; const float* bhh[4]; };

__device__ __forceinline__ unsigned short f2bf(float f) {
    unsigned u = __float_as_uint(f);
    u = (u + 0x7FFFu + ((u >> 16) & 1u)) >> 16;   // RNE f32->bf16
    return (unsigned short)u;
}

// ---------------- weight repack + bias fold ----------------
__global__ __launch_bounds__(64) void k_prepw(PrepArgs pa) {
    int r = blockIdx.x;                 // 0..1535
    int pq = r / 768, col = r % 768;
    int dir = col / 384, within = col % 384, gate = within / 128;
    int idx = pq * 2 + dir;             // {p_f,p_b,q_f,q_b}
    const float* wsrc = pa.wih[idx] + within * E_;
    __hip_bfloat16* dst = pq ? g_wq[col] : g_wp[col];
    for (int c = threadIdx.x; c < KP; c += 64)
        dst[c] = __float2bfloat16(c < E_ ? wsrc[c] : 0.f);
    if (threadIdx.x == 0) {
        float bsum = pa.bih[idx][within] + (gate < 2 ? pa.bhh[idx][within] : 0.f);
        (pq ? g_biasq : g_biasp)[col] = bsum;
        if (within >= 256) g_biasn[idx][within - 256] = pa.bhh[idx][within];
    }
}

// ---------------- whh -> MFMA B-fragment repack (bf16) ----------------
__global__ __launch_bounds__(512) void k_prepw2(const float* w0, const float* w1,
                                               const float* w2, const float* w3) {
    int widx = blockIdx.x;              // 0..3
    const float* whh = widx == 0 ? w0 : widx == 1 ? w1 : widx == 2 ? w2 : w3;
    int tid = threadIdx.x, l = tid & 63, w = tid >> 6;
    int l15 = l & 15, lg = l >> 4;
    int j = w * 16 + l15;
    #pragma unroll
    for (int f = 0; f < 12; f++) {
        int g = f >> 2, ks = f & 3;
        const float* src = whh + (long)(g * 128 + j) * HH_ + ks * 32 + lg * 8;
        bf16x8 v;
        #pragma unroll
        for (int e = 0; e < 8; e++) v[e] = (short)f2bf(src[e]);
        ((bf16x8*)g_whhrep)[(widx * 12 + f) * 512 + tid] = v;
    }
}

// ---------------- embedding gather (T-MAJOR rows, f32 -> bf16) ----------------
__global__ __launch_bounds__(256) void k_gather(const int* pass, const int* ques, const float* emb) {
    int row = blockIdx.x * 4 + (threadIdx.x >> 6);
    int lane = threadIdx.x & 63;
    const int* tsrc; __hip_bfloat16* dst; int r, T;
    if (row < BP) { r = row; tsrc = pass; dst = &g_ep[r][0]; T = P_; }
    else          { r = row - BP; tsrc = ques; dst = &g_eq[r][0]; T = Q_; }
    int b = r & 31, t = r >> 5;         // t-major
    int tk = tsrc[b * T + t];
    const float* src = emb + (long)tk * E_;
    #pragma unroll
    for (int i = 0; i < 5; i++) {
        int c = i * 64 + lane;
        float v = (c < E_) ? src[c] : 0.f;
        dst[c] = __float2bfloat16(v);
    }
}

// ---------------- input-projection GEMM -> bf16 staged-tile layout ----------------
__global__ __launch_bounds__(256) void k_gemm(int isQ) {
    const __hip_bfloat16* A  = isQ ? &g_eq[0][0] : &g_ep[0][0];
    const __hip_bfloat16* Bw = isQ ? &g_wq[0][0] : &g_wp[0][0];
    const float* bias = isQ ? g_biasq : g_biasp;
    short* Xt = isQ ? g_xtq : g_xtp;
    const int T = isQ ? Q_ : P_;
    __shared__ __hip_bfloat16 As[128][40];
    __shared__ __hip_bfloat16 Bs[128][40];
    int m0 = blockIdx.x * 128, n0 = blockIdx.y * 128;
    int tid = threadIdx.x, lane = tid & 63, w = tid >> 6;
    int wm = (w & 1) * 64, wn = (w >> 1) * 64;
    f32x4 acc[4][4] = {};
    int lr = tid >> 1, lc = (tid & 1) * 16;
    for (int kt = 0; kt < KP; kt += 32) {
        *(bf16x8*)&As[lr][lc]   = *(const bf16x8*)&A [(m0 + lr) * KP + kt + lc];
        *(bf16x8*)&As[lr][lc+8] = *(const bf16x8*)&A [(m0 + lr) * KP + kt + lc + 8];
        *(bf16x8*)&Bs[lr][lc]   = *(const bf16x8*)&Bw[(n0 + lr) * KP + kt + lc];
        *(bf16x8*)&Bs[lr][lc+8] = *(const bf16x8*)&Bw[(n0 + lr) * KP + kt + lc + 8];
        __syncthreads();
        int kb = (lane >> 4) * 8, l15 = lane & 15;
        bf16x8 af[4], bfr[4];
        #pragma unroll
        for (int i = 0; i < 4; i++) af[i]  = *(bf16x8*)&As[wm + i*16 + l15][kb];
        #pragma unroll
        for (int j = 0; j < 4; j++) bfr[j] = *(bf16x8*)&Bs[wn + j*16 + l15][kb];
        #pragma unroll
        for (int i = 0; i < 4; i++)
            #pragma unroll
            for (int j = 0; j < 4; j++)
                acc[i][j] = __builtin_amdgcn_mfma_f32_16x16x32_bf16(af[i], bfr[j], acc[i][j], 0, 0, 0);
        __syncthreads();
    }
    int l15 = lane & 15, lr4 = (lane >> 4) * 4;
    #pragma unroll
    for (int jj = 0; jj < 4; jj++) {
        int n = n0 + wn + jj * 16 + l15;
        float bn = bias[n];
        int dirn = n >= 384;
        int col = n - dirn * 384;
        short* Cx = Xt + (long)dirn * T * 2 * 384 * 16;
        #pragma unroll
        for (int i = 0; i < 4; i++) {
            int mb = m0 + wm + i * 16 + lr4;     // mb%4==0 -> q=0..3 same t, b consec
            int t = mb >> 5, b = mb & 31;
            int g = b >> 4, bi = b & 15;
            unsigned u0 = (unsigned)f2bf(acc[i][jj][0] + bn) |
                          ((unsigned)f2bf(acc[i][jj][1] + bn) << 16);
            unsigned u1 = (unsigned)f2bf(acc[i][jj][2] + bn) |
                          ((unsigned)f2bf(acc[i][jj][3] + bn) << 16);
            uint2 pk = {u0, u1};
            *(uint2*)&Cx[((long)(t * 2 + g) * 384 + col) * 16 + bi] = pk;
        }
    }
}

// ---------------- z-gate poison for masked steps (freeze h exactly) ----------------
__global__ __launch_bounds__(128) void k_maskz(const int* pass, const int* ques) {
    int row = blockIdx.x;
    int tid = threadIdx.x;
    int isQ = row >= BP;
    int rr = isQ ? row - BP : row;
    int T = isQ ? Q_ : P_;
    int b = rr / T, t = rr % T;
    int tkn = isQ ? ques[rr] : pass[rr];
    if (tkn != 0) return;
    short* xt = isQ ? g_xtq : g_xtp;
    unsigned short big = f2bf(1e9f);
    int g = b >> 4, bi = b & 15;
    long base = ((long)(t * 2 + g) * 384 + 128 + tid) * 16 + bi;
    xt[base] = (short)big;
    xt[base + (long)T * 2 * 384 * 16] = (short)big;
}

// ---------------- GRU recurrence: F/B interleaved chains per block ----------------
// 4 blocks x 512 threads. Block = (isQ, chain-group g); runs BOTH directions'
// chains interleaved in program order: set F's LDS write->read round-trip is
// covered by set B's MFMA+gates (in-order issue!), and vice versa across the
// loop edge. One barrier per iteration (= 2 chain-steps). GLLs issued at the
// TOP of the body; barrier waits vmcnt(8) = this iter's 4 GLLs.
#define GLL(gp, lp) __builtin_amdgcn_global_load_lds( \
    (const __attribute__((address_space(1))) unsigned int*)(gp), \
    (__attribute__((address_space(3))) unsigned int*)(lp), 16, 0, 0)

#define MFMA12(S)                                                              \
    acc0 = __builtin_amdgcn_mfma_f32_16x16x32_bf16(af##S##0, b##S##00, acc0, 0, 0, 0); \
    acc1 = __builtin_amdgcn_mfma_f32_16x16x32_bf16(af##S##0, b##S##10, acc1, 0, 0, 0); \
    acc2 = __builtin_amdgcn_mfma_f32_16x16x32_bf16(af##S##0, b##S##20, acc2, 0, 0, 0); \
    acc0 = __builtin_amdgcn_mfma_f32_16x16x32_bf16(af##S##1, b##S##01, acc0, 0, 0, 0); \
    acc1 = __builtin_amdgcn_mfma_f32_16x16x32_bf16(af##S##1, b##S##11, acc1, 0, 0, 0); \
    acc2 = __builtin_amdgcn_mfma_f32_16x16x32_bf16(af##S##1, b##S##21, acc2, 0, 0, 0); \
    acc0 = __builtin_amdgcn_mfma_f32_16x16x32_bf16(af##S##2, b##S##02, acc0, 0, 0, 0); \
    acc1 = __builtin_amdgcn_mfma_f32_16x16x32_bf16(af##S##2, b##S##12, acc1, 0, 0, 0); \
    acc2 = __builtin_amdgcn_mfma_f32_16x16x32_bf16(af##S##2, b##S##22, acc2, 0, 0, 0); \
    acc0 = __builtin_amdgcn_mfma_f32_16x16x32_bf16(af##S##3, b##S##03, acc0, 0, 0, 0); \
    acc1 = __builtin_amdgcn_mfma_f32_16x16x32_bf16(af##S##3, b##S##13, acc1, 0, 0, 0); \
    acc2 = __builtin_amdgcn_mfma_f32_16x16x32_bf16(af##S##3, b##S##23, acc2, 0, 0, 0);

#define GATES(D0, D1, D2, BNN, HOLD, HW, OROW)                                 \
    { char* hw_ = (HW); float* orow_ = (OROW);                                 \
      float xr_[4] = { __uint_as_float((D0).x << 16), __uint_as_float((D0).x & 0xFFFF0000u), \
                       __uint_as_float((D0).y << 16), __uint_as_float((D0).y & 0xFFFF0000u) }; \
      float xz_[4] = { __uint_as_float((D1).x << 16), __uint_as_float((D1).x & 0xFFFF0000u), \
                       __uint_as_float((D1).y << 16), __uint_as_float((D1).y & 0xFFFF0000u) }; \
      float xn_[4] = { __uint_as_float((D2).x << 16), __uint_as_float((D2).x & 0xFFFF0000u), \
                       __uint_as_float((D2).y << 16), __uint_as_float((D2).y & 0xFFFF0000u) }; \
      _Pragma("unroll")                                                        \
      for (int q = 0; q < 4; q++) {                                            \
        float rg = __builtin_amdgcn_rcpf(1.f + __expf(-(acc0[q] + xr_[q])));   \
        float zg = __builtin_amdgcn_rcpf(1.f + __expf(-(acc1[q] + xz_[q])));   \
        float ta = __builtin_amdgcn_fmed3f(fmaf(rg, acc2[q] + (BNN), xn_[q]), -15.f, 15.f); \
        float e2 = __expf(2.f * ta);                                           \
        float th = fmaf(-2.f, __builtin_amdgcn_rcpf(e2 + 1.f), 1.f);           \
        float hv = fmaf(zg, (HOLD)[q] - th, th);                               \
        (HOLD)[q] = hv;                                                        \
        *(__hip_bfloat16*)(hw_ + ((vw ^ (q << 4)) + q * 256)) = __float2bfloat16(hv); \
        orow_[q * TH] = hv;                                                    \
      } }

__global__ __launch_bounds__(512, 1) void k_gru() {
    int blk = blockIdx.x;               // [isQ][g]
    int isQ = blk >> 1, g = blk & 1, bbase = g * 16;
    const int T = isQ ? Q_ : P_;
    const char* gxF = (const char*)(isQ ? g_xtq : g_xtp);
    const char* gxB = gxF + (long)T * 2 * 12288;      // dir=1 tiles
    float* outp = isQ ? g_qenc : g_penc;
    int widxF = isQ * 2, widxB = widxF + 1;
    int tid = threadIdx.x, l = tid & 63, w = tid >> 6;
    int l15 = l & 15, lg = l >> 4;
    int j = w * 16 + l15, m0 = lg * 4;

    const bf16x8* wrpF = (const bf16x8*)g_whhrep + (long)widxF * 12 * 512 + tid;
    const bf16x8* wrpB = (const bf16x8*)g_whhrep + (long)widxB * 12 * 512 + tid;
    bf16x8 bF00 = wrpF[0*512],  bF01 = wrpF[1*512],  bF02 = wrpF[2*512],  bF03 = wrpF[3*512];
    bf16x8 bF10 = wrpF[4*512],  bF11 = wrpF[5*512],  bF12 = wrpF[6*512],  bF13 = wrpF[7*512];
    bf16x8 bF20 = wrpF[8*512],  bF21 = wrpF[9*512],  bF22 = wrpF[10*512], bF23 = wrpF[11*512];
    bf16x8 bB00 = wrpB[0*512],  bB01 = wrpB[1*512],  bB02 = wrpB[2*512],  bB03 = wrpB[3*512];
    bf16x8 bB10 = wrpB[4*512],  bB11 = wrpB[5*512],  bB12 = wrpB[6*512],  bB13 = wrpB[7*512];
    bf16x8 bB20 = wrpB[8*512],  bB21 = wrpB[9*512],  bB22 = wrpB[10*512], bB23 = wrpB[11*512];
    float bnnF = g_biasn[widxF][j];
    float bnnB = g_biasn[widxB][j];

    __shared__ __align__(16) char lds[65536];
    char* lxF0 = lds;            char* lxF1 = lds + 12288;
    char* lxB0 = lds + 24576;    char* lxB1 = lds + 36864;
    char* hF   = lds + 49152;    // 2 x 4096
    char* hB   = lds + 57344;    // 2 x 4096

    // LDS swizzle addresses for the h exchange (validated rounds 4-7)
    int smz = (m0 & 7) << 4;
    int vw  = m0 * 256 + ((j * 2) ^ smz);
    int sw  = (l15 & 7) << 4;
    int vr0 = l15 * 256 + ((0 * 64 + lg * 16) ^ sw);
    int vr1 = l15 * 256 + ((1 * 64 + lg * 16) ^ sw);
    int vr2 = l15 * 256 + ((2 * 64 + lg * 16) ^ sw);
    int vr3 = l15 * 256 + ((3 * 64 + lg * 16) ^ sw);
    int xoff = j * 32 + m0 * 2;         // [col][chain] bf16 tile (consistent w/ gemm)

    const int TH = T * H_;
    int ooffF = ((bbase + m0) * T + 0)       * H_ + j;          // dir 0, t=0
    int ooffB = ((bbase + m0) * T + (T - 1)) * H_ + HH_ + j;    // dir 1, t=T-1

    // prologue: stage F tile t=0 and B tile t=T-1 into buffer 0 of each
    {
        const char* gtF = gxF + (long)(0 * 2 + g) * 12288;
        const char* gtB = gxB + (long)((T - 1) * 2 + g) * 12288;
        GLL(gtF + tid * 16, lxF0 + (w << 10));
        if (w < 4) GLL(gtF + 8192 + tid * 16, lxF0 + 8192 + (w << 10));
        GLL(gtB + tid * 16, lxB0 + (w << 10));
        if (w < 4) GLL(gtB + 8192 + tid * 16, lxB0 + 8192 + (w << 10));
    }
    asm volatile("s_waitcnt vmcnt(0) lgkmcnt(0)\n\ts_barrier" ::: "memory");
    uint2 dF0 = *(const uint2*)(lxF0 + xoff);
    uint2 dF1 = *(const uint2*)(lxF0 + xoff + 4096);
    uint2 dF2 = *(const uint2*)(lxF0 + xoff + 8192);
    uint2 dB0 = *(const uint2*)(lxB0 + xoff);
    uint2 dB1 = *(const uint2*)(lxB0 + xoff + 4096);
    uint2 dB2 = *(const uint2*)(lxB0 + xoff + 8192);

    f32x4 holdF = {0.f, 0.f, 0.f, 0.f}, holdB = holdF;
    bf16x8 z8 = {0,0,0,0,0,0,0,0};
    bf16x8 afF0 = z8, afF1 = z8, afF2 = z8, afF3 = z8;
    bf16x8 afB0 = z8, afB1 = z8, afB2 = z8, afB3 = z8;

    for (int st = 0; st < T; st++) {
        int n1 = (st + 1 < T) ? st + 1 : T - 1;
        char* sxF = (n1 & 1) ? lxF1 : lxF0;       // stage target (also read below)
        char* sxB = (n1 & 1) ? lxB1 : lxB0;
        // stage next-step tiles FIRST (complete by this iter's barrier: vmcnt(8))
        {
            const char* gtF = gxF + (long)(n1 * 2 + g) * 12288;
            const char* gtB = gxB + (long)((T - 1 - n1) * 2 + g) * 12288;
            GLL(gtF + tid * 16, sxF + (w << 10));
            if (w < 4) GLL(gtF + 8192 + tid * 16, sxF + 8192 + (w << 10));
            GLL(gtB + tid * 16, sxB + (w << 10));
            if (w < 4) GLL(gtB + 8192 + tid * 16, sxB + 8192 + (w << 10));
        }
        char* hwF = hF + (st & 1) * 4096;
        char* hwB = hB + (st & 1) * 4096;
        // ---- set F: MFMA + gates + h-write + out-store ----
        {
            f32x4 acc0 = {0.f,0.f,0.f,0.f}, acc1 = acc0, acc2 = acc0;
            MFMA12(F)
            GATES(dF0, dF1, dF2, bnnF, holdF, hwF, outp + ooffF)
        }
        // ---- set B (fills F's write->barrier->read latency) ----
        {
            f32x4 acc0 = {0.f,0.f,0.f,0.f}, acc1 = acc0, acc2 = acc0;
            MFMA12(B)
            GATES(dB0, dB1, dB2, bnnB, holdB, hwB, outp + ooffB)
        }
        // barrier: this iter's 4 GLLs complete (8 stores may stay in flight),
        // both sets' h ds_writes drained.
        asm volatile("s_waitcnt vmcnt(8) lgkmcnt(0)\n\ts_barrier" ::: "memory");
        // reads for next iteration
        afF0 = *(const bf16x8*)(hwF + vr0);
        afF1 = *(const bf16x8*)(hwF + vr1);
        afF2 = *(const bf16x8*)(hwF + vr2);
        afF3 = *(const bf16x8*)(hwF + vr3);
        afB0 = *(const bf16x8*)(hwB + vr0);
        afB1 = *(const bf16x8*)(hwB + vr1);
        afB2 = *(const bf16x8*)(hwB + vr2);
        afB3 = *(const bf16x8*)(hwB + vr3);
        dF0 = *(const uint2*)(sxF + xoff);
        dF1 = *(const uint2*)(sxF + xoff + 4096);
        dF2 = *(const uint2*)(sxF + xoff + 8192);
        dB0 = *(const uint2*)(sxB + xoff);
        dB1 = *(const uint2*)(sxB + xoff + 4096);
        dB2 = *(const uint2*)(sxB + xoff + 8192);
        ooffF += H_;
        ooffB -= H_;
    }
}

// ---------------- fused attention + output heads ----------------
#define QPAD 260
__global__ __launch_bounds__(256) void k_attn(const int* pass, const int* ques,
        const float* attn_w, const float* attn_b, const float* start_w,
        const float* start_b, const float* end_w, const float* end_b, float* out) {
    __shared__ float qs[Q_][QPAD];
    __shared__ float pw3[H_];
    __shared__ float lrow[Q_];
    __shared__ float probs[Q_];
    __shared__ float s2v[Q_];
    __shared__ int   qmS[Q_];
    __shared__ float red[4], redA[4], redB[4];
    __shared__ float awpart[4][QPAD];
    int b = blockIdx.x >> 6, pch = blockIdx.x & 63;
    int tid = threadIdx.x, lane = tid & 63, wid = tid >> 6;
    for (int i = tid; i < Q_ * H_; i += 256) {
        int q = i >> 8, h = i & 255;
        qs[q][h] = g_qenc[(long)(b * Q_ + q) * H_ + h];
    }
    if (tid < Q_) qmS[tid] = (ques[b * Q_ + tid] != 0);
    __syncthreads();
    int q4 = tid >> 2, part = tid & 3;
    {   // s2[q] = dot(qenc[q], w2)
        float p2 = 0.f;
        #pragma unroll 8
        for (int i = 0; i < 64; i++)
            p2 += qs[q4][part * 64 + i] * attn_w[256 + part * 64 + i];
        p2 += __shfl_xor(p2, 1);
        p2 += __shfl_xor(p2, 2);
        if (part == 0) s2v[q4] = p2;
    }
    __syncthreads();
    float ab = attn_b[0], sb = start_b[0], ebv = end_b[0];
    for (int pi = 0; pi < 8; pi++) {
        int p = pch * 8 + pi;
        float pv = g_penc[(long)(b * P_ + p) * H_ + tid];
        pw3[tid] = pv * attn_w[512 + tid];
        float r1 = pv * attn_w[tid];
        #pragma unroll
        for (int s = 1; s < 64; s <<= 1) r1 += __shfl_xor(r1, s);
        if (lane == 0) red[wid] = r1;
        __syncthreads();                                  // (A) pw3 + red
        float s1 = red[0] + red[1] + red[2] + red[3];
        float acc = 0.f;
        #pragma unroll
        for (int i = 0; i < 16; i++) {
            float4 qv = *(const float4*)&qs[q4][part * 64 + i * 4];
            float4 wv = *(const float4*)&pw3[part * 64 + i * 4];
            acc += qv.x * wv.x + qv.y * wv.y + qv.z * wv.z + qv.w * wv.w;
        }
        acc += __shfl_xor(acc, 1);
        acc += __shfl_xor(acc, 2);
        if (part == 0) lrow[q4] = qmS[q4] ? (s1 + s2v[q4] + acc + ab) : NEG;
        __syncthreads();                                  // (B) lrow
        if (tid < 64) {
            float v = lrow[tid];
            float m = v;
            #pragma unroll
            for (int s = 1; s < 64; s <<= 1) m = fmaxf(m, __shfl_xor(m, s));
            float e = __expf(v - m);
            float ss = e;
            #pragma unroll
            for (int s = 1; s < 64; s <<= 1) ss += __shfl_xor(ss, s);
            probs[tid] = e / ss;
        }
        __syncthreads();                                  // (C) probs
        float4 aw4 = {0.f, 0.f, 0.f, 0.f};
        #pragma unroll
        for (int qq = 0; qq < 16; qq++) {
            int q = wid * 16 + qq;
            float pq = probs[q];
            float4 qv = *(const float4*)&qs[q][lane * 4];
            aw4.x = fmaf(pq, qv.x, aw4.x);
            aw4.y = fmaf(pq, qv.y, aw4.y);
            aw4.z = fmaf(pq, qv.z, aw4.z);
            aw4.w = fmaf(pq, qv.w, aw4.w);
        }
        *(float4*)&awpart[wid][lane * 4] = aw4;
        __syncthreads();                                  // (D0) awpart
        float aw = awpart[0][tid] + awpart[1][tid] + awpart[2][tid] + awpart[3][tid];
        float spv = pv * start_w[tid] + aw * start_w[256 + tid] + pv * aw * start_w[512 + tid];
        float epv = pv * end_w[tid]   + aw * end_w[256 + tid]   + pv * aw * end_w[512 + tid];
        #pragma unroll
        for (int s = 1; s < 64; s <<= 1) {
            spv += __shfl_xor(spv, s);
            epv += __shfl_xor(epv, s);
        }
        if (lane == 0) { redA[wid] = spv; redB[wid] = epv; }
        __syncthreads();                                  // (D) redA/B
        if (tid == 0) {
            int pm = (pass[b * P_ + p] != 0);
            float sv = redA[0] + redA[1] + redA[2] + redA[3] + sb;
            float ev = redB[0] + redB[1] + redB[2] + redB[3] + ebv;
            out[b * P_ + p]       = pm ? sv : NEG;
            out[BP + b * P_ + p]  = pm ? ev : NEG;
        }
        __syncthreads();                                  // (E) end of row
    }
}

// ---------------- log_softmax over P per (batch, start/end) ----------------
__global__ __launch_bounds__(256) void k_lsm(float* out) {
    int b = blockIdx.x >> 1, which = blockIdx.x & 1;
    const float* src = out + which * BP + b * P_;
    int tid = threadIdx.x;
    float v0 = src[tid], v1 = src[tid + 256];
    __shared__ float red[4];
    float m = fmaxf(v0, v1);
    #pragma unroll
    for (int s = 1; s < 64; s <<= 1) m = fmaxf(m, __shfl_xor(m, s));
    if ((tid & 63) == 0) red[tid >> 6] = m;
    __syncthreads();
    m = fmaxf(fmaxf(red[0], red[1]), fmaxf(red[2], red[3]));
    __syncthreads();
    float ss = __expf(v0 - m) + __expf(v1 - m);
    #pragma unroll
    for (int s = 1; s < 64; s <<= 1) ss += __shfl_xor(ss, s);
    if ((tid & 63) == 0) red[tid >> 6] = ss;
    __syncthreads();
    float lse = m + logf(red[0] + red[1] + red[2] + red[3]);
    float* dst = out + (2 + which) * BP + b * P_;
    dst[tid] = v0 - lse;
    dst[tid + 256] = v1 - lse;
}

extern "C" void kernel_launch(void* const* d_in, const int* in_sizes, int n_in,
                              void* d_out, int out_size, void* d_ws, size_t ws_size,
                              hipStream_t stream) {
    const int* pass = (const int*)d_in[0];
    const int* ques = (const int*)d_in[1];
    const float* emb = (const float*)d_in[2];
    PrepArgs pa;
    const float* whh[4];
    const int base[4] = {3, 7, 11, 15};   // p_f, p_b, q_f, q_b blocks of 4 inputs
    for (int i = 0; i < 4; i++) {
        pa.wih[i] = (const float*)d_in[base[i] + 0];
        whh[i]    = (const float*)d_in[base[i] + 1];
        pa.bih[i] = (const float*)d_in[base[i] + 2];
        pa.bhh[i] = (const float*)d_in[base[i] + 3];
    }
    const float* attn_w  = (const float*)d_in[19];
    const float* attn_b  = (const float*)d_in[20];
    const float* start_w = (const float*)d_in[21];
    const float* start_b = (const float*)d_in[22];
    const float* end_w   = (const float*)d_in[23];
    const float* end_b   = (const float*)d_in[24];
    float* out = (float*)d_out;

    k_prepw <<<dim3(1536), dim3(64), 0, stream>>>(pa);
    k_prepw2<<<dim3(4), dim3(512), 0, stream>>>(whh[0], whh[1], whh[2], whh[3]);
    k_gather<<<dim3((BP + BQ) / 4), dim3(256), 0, stream>>>(pass, ques, emb);
    k_gemm  <<<dim3(BP / 128, 6), dim3(256), 0, stream>>>(0);
    k_gemm  <<<dim3(BQ / 128, 6), dim3(256), 0, stream>>>(1);
    k_maskz <<<dim3(BP + BQ), dim3(128), 0, stream>>>(pass, ques);
    k_gru   <<<dim3(4), dim3(512), 0, stream>>>();
    k_attn  <<<dim3(B_ * 64), dim3(256), 0, stream>>>(pass, ques, attn_w, attn_b,
                                                      start_w, start_b, end_w, end_b, out);
    k_lsm   <<<dim3(64), dim3(256), 0, stream>>>(out);
}

// Round 10
// 561.738 us; speedup vs baseline: 1.7944x; 1.7944x over previous
//
#include <hip/hip_runtime.h>
#include <hip/hip_bf16.h>

#define B_ 32
#define P_ 512
#define Q_ 64
#define E_ 300
#define KP 320          // E padded to multiple of 32 for MFMA K-steps
#define H_ 256
#define HH_ 128
#define NEG (-1e7f)
#define BP (B_*P_)
#define BQ (B_*Q_)

typedef __attribute__((ext_vector_type(8))) short bf16x8;
typedef __attribute__((ext_vector_type(4))) float f32x4;
typedef _Float16 half2v __attribute__((ext_vector_type(2)));
typedef unsigned int u32;

// ---- static device workspace (fully rewritten every call) ----
// Embeddings gathered T-MAJOR: row = t*32 + b
__device__ __hip_bfloat16 g_ep[BP][KP];
__device__ __hip_bfloat16 g_eq[BQ][KP];
__device__ __hip_bfloat16 g_wp[768][KP];     // combined passage wih
__device__ __hip_bfloat16 g_wq[768][KP];     // combined question wih
__device__ float g_biasp[768];               // bih (+ bhh for r,z gates)
__device__ float g_biasq[768];
__device__ float g_biasn[4][HH_];            // bhh n-gate bias per weight set
__device__ uint4 g_whhw[4*128*48];           // [widx][j][gate][16] f16-packed whh rows
__device__ float g_xtp[2L*P_*B_*384];        // passage x-proj, [dir][t][b][384] f32
__device__ float g_xtq[2L*Q_*B_*384];        // question x-proj
__device__ float g_penc[BP*H_];              // BiGRU passage encodings (f32)
__device__ float g_qenc[BQ*H_];              // BiGRU question encodings

struct PrepArgs { const float* wih[4]; const float* bih[4]; const float* bhh[4]; };

// ---------------- weight repack + bias fold ----------------
__global__ __launch_bounds__(64) void k_prepw(PrepArgs pa) {
    int r = blockIdx.x;                 // 0..1535
    int pq = r / 768, col = r % 768;
    int dir = col / 384, within = col % 384, gate = within / 128;
    int idx = pq * 2 + dir;             // {p_f,p_b,q_f,q_b}
    const float* wsrc = pa.wih[idx] + within * E_;
    __hip_bfloat16* dst = pq ? g_wq[col] : g_wp[col];
    for (int c = threadIdx.x; c < KP; c += 64)
        dst[c] = __float2bfloat16(c < E_ ? wsrc[c] : 0.f);
    if (threadIdx.x == 0) {
        float bsum = pa.bih[idx][within] + (gate < 2 ? pa.bhh[idx][within] : 0.f);
        (pq ? g_biasq : g_biasp)[col] = bsum;
        if (within >= 256) g_biasn[idx][within - 256] = pa.bhh[idx][within];
    }
}

// ---------------- whh -> per-thread f16-packed rows ----------------
__global__ __launch_bounds__(128) void k_prepw2(const float* w0, const float* w1,
                                               const float* w2, const float* w3) {
    int widx = blockIdx.x;              // 0..3
    const float* whh = widx == 0 ? w0 : widx == 1 ? w1 : widx == 2 ? w2 : w3;
    int j = threadIdx.x;                // hidden col 0..127
    uint4* dst = g_whhw + ((long)widx * 128 + j) * 48;
    for (int g = 0; g < 3; g++)
        for (int i = 0; i < 16; i++) {
            const float* src = whh + (long)(g * 128 + j) * HH_ + i * 8;
            u32 p[4];
            #pragma unroll
            for (int e = 0; e < 4; e++) {
                half2v hp;
                hp[0] = (_Float16)src[2 * e];
                hp[1] = (_Float16)src[2 * e + 1];
                p[e] = __builtin_bit_cast(u32, hp);
            }
            dst[g * 16 + i] = make_uint4(p[0], p[1], p[2], p[3]);
        }
}

// ---------------- embedding gather (T-MAJOR rows, f32 -> bf16) ----------------
__global__ __launch_bounds__(256) void k_gather(const int* pass, const int* ques, const float* emb) {
    int row = blockIdx.x * 4 + (threadIdx.x >> 6);
    int lane = threadIdx.x & 63;
    const int* tsrc; __hip_bfloat16* dst; int r, T;
    if (row < BP) { r = row; tsrc = pass; dst = &g_ep[r][0]; T = P_; }
    else          { r = row - BP; tsrc = ques; dst = &g_eq[r][0]; T = Q_; }
    int b = r & 31, t = r >> 5;         // t-major
    int tk = tsrc[b * T + t];
    const float* src = emb + (long)tk * E_;
    #pragma unroll
    for (int i = 0; i < 5; i++) {
        int c = i * 64 + lane;
        float v = (c < E_) ? src[c] : 0.f;
        dst[c] = __float2bfloat16(v);
    }
}

// ---------------- input-projection GEMM -> f32 [dir][t][b][384] ----------------
__global__ __launch_bounds__(256) void k_gemm(int isQ) {
    const __hip_bfloat16* A  = isQ ? &g_eq[0][0] : &g_ep[0][0];
    const __hip_bfloat16* Bw = isQ ? &g_wq[0][0] : &g_wp[0][0];
    const float* bias = isQ ? g_biasq : g_biasp;
    float* Xt = isQ ? g_xtq : g_xtp;
    const int T = isQ ? Q_ : P_;
    __shared__ __hip_bfloat16 As[128][40];
    __shared__ __hip_bfloat16 Bs[128][40];
    int m0 = blockIdx.x * 128, n0 = blockIdx.y * 128;
    int tid = threadIdx.x, lane = tid & 63, w = tid >> 6;
    int wm = (w & 1) * 64, wn = (w >> 1) * 64;
    f32x4 acc[4][4] = {};
    int lr = tid >> 1, lc = (tid & 1) * 16;
    for (int kt = 0; kt < KP; kt += 32) {
        *(bf16x8*)&As[lr][lc]   = *(const bf16x8*)&A [(m0 + lr) * KP + kt + lc];
        *(bf16x8*)&As[lr][lc+8] = *(const bf16x8*)&A [(m0 + lr) * KP + kt + lc + 8];
        *(bf16x8*)&Bs[lr][lc]   = *(const bf16x8*)&Bw[(n0 + lr) * KP + kt + lc];
        *(bf16x8*)&Bs[lr][lc+8] = *(const bf16x8*)&Bw[(n0 + lr) * KP + kt + lc + 8];
        __syncthreads();
        int kb = (lane >> 4) * 8, l15 = lane & 15;
        bf16x8 af[4], bfr[4];
        #pragma unroll
        for (int i = 0; i < 4; i++) af[i]  = *(bf16x8*)&As[wm + i*16 + l15][kb];
        #pragma unroll
        for (int j = 0; j < 4; j++) bfr[j] = *(bf16x8*)&Bs[wn + j*16 + l15][kb];
        #pragma unroll
        for (int i = 0; i < 4; i++)
            #pragma unroll
            for (int j = 0; j < 4; j++)
                acc[i][j] = __builtin_amdgcn_mfma_f32_16x16x32_bf16(af[i], bfr[j], acc[i][j], 0, 0, 0);
        __syncthreads();
    }
    int l15 = lane & 15, lr4 = (lane >> 4) * 4;
    #pragma unroll
    for (int jj = 0; jj < 4; jj++) {
        int n = n0 + wn + jj * 16 + l15;
        float bn = bias[n];
        int dirn = n >= 384;
        int col = n - dirn * 384;
        float* Cx = Xt + (long)dirn * T * B_ * 384;
        #pragma unroll
        for (int i = 0; i < 4; i++) {
            int mb = m0 + wm + i * 16 + lr4;     // T-major rows: t = m>>5, b = m&31
            int t = mb >> 5, bb = mb & 31;
            #pragma unroll
            for (int q = 0; q < 4; q++)
                Cx[((long)t * B_ + bb + q) * 384 + col] = acc[i][jj][q] + bn;
        }
    }
}

// ---------------- z-gate poison for masked steps (freeze h exactly) ----------------
__global__ __launch_bounds__(128) void k_maskz(const int* pass, const int* ques) {
    int row = blockIdx.x;
    int tid = threadIdx.x;
    int isQ = row >= BP;
    int rr = isQ ? row - BP : row;
    int T = isQ ? Q_ : P_;
    int b = rr / T, t = rr % T;
    int tkn = isQ ? ques[rr] : pass[rr];
    if (tkn != 0) return;
    float* xt = isQ ? g_xtq : g_xtp;
    xt[((long)0 * T * B_ + (long)t * B_ + b) * 384 + 128 + tid] = 1e9f;
    xt[((long)1 * T * B_ + (long)t * B_ + b) * 384 + 128 + tid] = 1e9f;
}

// ---------------- GRU recurrence: 1 thread = 1 hidden col, f16 dot2 ----------------
// 128 blocks (one per chain) x 128 threads (2 waves). Thread j holds all 3 gate
// rows of whh for col j in 48 uint4 (192 VGPR, f16 pairs), computes full dots
// via v_dot2_f32_f16 and gates IN-PLACE: no partial-sum LDS, no divergence.
// h exchange: 1 ds_write_b16 + 16 uniform-broadcast ds_read_b128 per wave,
// double-buffered, ONE lgkmcnt-only barrier per step.
#define D1(A, WU, HU) A = __builtin_amdgcn_fdot2( \
    __builtin_bit_cast(half2v, (WU)), __builtin_bit_cast(half2v, (HU)), A, false);
#define D4(A, W, H) D1(A,(W).x,(H).x) D1(A,(W).y,(H).y) D1(A,(W).z,(H).z) D1(A,(W).w,(H).w)
#define DOTG(G, A0, A1) \
    D4(A0, w##G##0,  h0)  D4(A1, w##G##1,  h1)  D4(A0, w##G##2,  h2)  D4(A1, w##G##3,  h3)  \
    D4(A0, w##G##4,  h4)  D4(A1, w##G##5,  h5)  D4(A0, w##G##6,  h6)  D4(A1, w##G##7,  h7)  \
    D4(A0, w##G##8,  h8)  D4(A1, w##G##9,  h9)  D4(A0, w##G##10, h10) D4(A1, w##G##11, h11) \
    D4(A0, w##G##12, h12) D4(A1, w##G##13, h13) D4(A0, w##G##14, h14) D4(A1, w##G##15, h15)
#define LW(G) \
    uint4 w##G##0  = wp[(G)*16+0],  w##G##1  = wp[(G)*16+1],  w##G##2  = wp[(G)*16+2],  \
          w##G##3  = wp[(G)*16+3],  w##G##4  = wp[(G)*16+4],  w##G##5  = wp[(G)*16+5],  \
          w##G##6  = wp[(G)*16+6],  w##G##7  = wp[(G)*16+7],  w##G##8  = wp[(G)*16+8],  \
          w##G##9  = wp[(G)*16+9],  w##G##10 = wp[(G)*16+10], w##G##11 = wp[(G)*16+11], \
          w##G##12 = wp[(G)*16+12], w##G##13 = wp[(G)*16+13], w##G##14 = wp[(G)*16+14], \
          w##G##15 = wp[(G)*16+15];

__global__ __launch_bounds__(128, 1) void k_gru() {
    int blk = blockIdx.x;               // [isQ][dir][b]
    int isQ = blk >> 6, loc = blk & 63, dir = loc >> 5, b = loc & 31;
    const int T = isQ ? Q_ : P_;
    const float* xt = (isQ ? g_xtq : g_xtp) + (long)dir * T * B_ * 384;
    float* outp = isQ ? g_qenc : g_penc;
    int widx = isQ * 2 + dir;
    int j = threadIdx.x;                // hidden col 0..127
    const uint4* wp = g_whhw + ((long)widx * 128 + j) * 48;
    LW(0) LW(1) LW(2)
    float bnn = g_biasn[widx][j];
    __shared__ uint hbuf[2][64];        // h as packed f16, double-buffered
    int t0 = dir ? T - 1 : 0;
    int sdt = dir ? -(B_ * 384) : (B_ * 384);
    int sdo = dir ? -H_ : H_;
    int off = (t0 * B_ + b) * 384 + j;
    int ooff = (b * T + t0) * H_ + dir * HH_ + j;
    float xr = xt[off], xz = xt[off + 128], xn = xt[off + 256];
    uint4 z4 = {0u, 0u, 0u, 0u};
    uint4 h0 = z4, h1 = z4, h2 = z4, h3 = z4, h4 = z4, h5 = z4, h6 = z4, h7 = z4,
          h8 = z4, h9 = z4, h10 = z4, h11 = z4, h12 = z4, h13 = z4, h14 = z4, h15 = z4;
    float hold = 0.f;
    for (int st = 0; st < T; st++) {
        int offn = off + ((st + 1 < T) ? sdt : 0);
        float nxr = xt[offn], nxz = xt[offn + 128], nxn = xt[offn + 256];
        float ar0 = 0.f, ar1 = 0.f, az0 = 0.f, az1 = 0.f, an0 = 0.f, an1 = 0.f;
        DOTG(0, ar0, ar1)
        DOTG(1, az0, az1)
        DOTG(2, an0, an1)
        // gates (masked steps: xz=1e9 -> z=1 -> h frozen exactly)
        float rg = __builtin_amdgcn_rcpf(1.f + __expf(-(ar0 + ar1 + xr)));
        float zg = __builtin_amdgcn_rcpf(1.f + __expf(-(az0 + az1 + xz)));
        float ta = __builtin_amdgcn_fmed3f(fmaf(rg, an0 + an1 + bnn, xn), -15.f, 15.f);
        float e2 = __expf(2.f * ta);
        float th = fmaf(-2.f, __builtin_amdgcn_rcpf(e2 + 1.f), 1.f);
        float hv = fmaf(zg, hold - th, th);
        hold = hv;
        outp[ooff] = hv;                             // fire-and-forget f32 store
        ((_Float16*)hbuf[st & 1])[j] = (_Float16)hv; // 2B h write, buffer st&1
        asm volatile("s_waitcnt lgkmcnt(0)\n\ts_barrier" ::: "memory");
        const uint4* hb = (const uint4*)hbuf[st & 1];
        h0 = hb[0];  h1 = hb[1];  h2 = hb[2];  h3 = hb[3];
        h4 = hb[4];  h5 = hb[5];  h6 = hb[6];  h7 = hb[7];
        h8 = hb[8];  h9 = hb[9];  h10 = hb[10]; h11 = hb[11];
        h12 = hb[12]; h13 = hb[13]; h14 = hb[14]; h15 = hb[15];
        off = offn; ooff += sdo;
        xr = nxr; xz = nxz; xn = nxn;
    }
}

// ---------------- fused attention + output heads ----------------
#define QPAD 260
__global__ __launch_bounds__(256) void k_attn(const int* pass, const int* ques,
        const float* attn_w, const float* attn_b, const float* start_w,
        const float* start_b, const float* end_w, const float* end_b, float* out) {
    __shared__ float qs[Q_][QPAD];
    __shared__ float pw3[H_];
    __shared__ float lrow[Q_];
    __shared__ float probs[Q_];
    __shared__ float s2v[Q_];
    __shared__ int   qmS[Q_];
    __shared__ float red[4], redA[4], redB[4];
    __shared__ float awpart[4][QPAD];
    int b = blockIdx.x >> 6, pch = blockIdx.x & 63;
    int tid = threadIdx.x, lane = tid & 63, wid = tid >> 6;
    for (int i = tid; i < Q_ * H_; i += 256) {
        int q = i >> 8, h = i & 255;
        qs[q][h] = g_qenc[(long)(b * Q_ + q) * H_ + h];
    }
    if (tid < Q_) qmS[tid] = (ques[b * Q_ + tid] != 0);
    __syncthreads();
    int q4 = tid >> 2, part = tid & 3;
    {   // s2[q] = dot(qenc[q], w2)
        float p2 = 0.f;
        #pragma unroll 8
        for (int i = 0; i < 64; i++)
            p2 += qs[q4][part * 64 + i] * attn_w[256 + part * 64 + i];
        p2 += __shfl_xor(p2, 1);
        p2 += __shfl_xor(p2, 2);
        if (part == 0) s2v[q4] = p2;
    }
    __syncthreads();
    float ab = attn_b[0], sb = start_b[0], ebv = end_b[0];
    for (int pi = 0; pi < 8; pi++) {
        int p = pch * 8 + pi;
        float pv = g_penc[(long)(b * P_ + p) * H_ + tid];
        pw3[tid] = pv * attn_w[512 + tid];
        float r1 = pv * attn_w[tid];
        #pragma unroll
        for (int s = 1; s < 64; s <<= 1) r1 += __shfl_xor(r1, s);
        if (lane == 0) red[wid] = r1;
        __syncthreads();                                  // (A) pw3 + red
        float s1 = red[0] + red[1] + red[2] + red[3];
        float acc = 0.f;
        #pragma unroll
        for (int i = 0; i < 16; i++) {
            float4 qv = *(const float4*)&qs[q4][part * 64 + i * 4];
            float4 wv = *(const float4*)&pw3[part * 64 + i * 4];
            acc += qv.x * wv.x + qv.y * wv.y + qv.z * wv.z + qv.w * wv.w;
        }
        acc += __shfl_xor(acc, 1);
        acc += __shfl_xor(acc, 2);
        if (part == 0) lrow[q4] = qmS[q4] ? (s1 + s2v[q4] + acc + ab) : NEG;
        __syncthreads();                                  // (B) lrow
        if (tid < 64) {
            float v = lrow[tid];
            float m = v;
            #pragma unroll
            for (int s = 1; s < 64; s <<= 1) m = fmaxf(m, __shfl_xor(m, s));
            float e = __expf(v - m);
            float ss = e;
            #pragma unroll
            for (int s = 1; s < 64; s <<= 1) ss += __shfl_xor(ss, s);
            probs[tid] = e / ss;
        }
        __syncthreads();                                  // (C) probs
        float4 aw4 = {0.f, 0.f, 0.f, 0.f};
        #pragma unroll
        for (int qq = 0; qq < 16; qq++) {
            int q = wid * 16 + qq;
            float pq = probs[q];
            float4 qv = *(const float4*)&qs[q][lane * 4];
            aw4.x = fmaf(pq, qv.x, aw4.x);
            aw4.y = fmaf(pq, qv.y, aw4.y);
            aw4.z = fmaf(pq, qv.z, aw4.z);
            aw4.w = fmaf(pq, qv.w, aw4.w);
        }
        *(float4*)&awpart[wid][lane * 4] = aw4;
        __syncthreads();                                  // (D0) awpart
        float aw = awpart[0][tid] + awpart[1][tid] + awpart[2][tid] + awpart[3][tid];
        float spv = pv * start_w[tid] + aw * start_w[256 + tid] + pv * aw * start_w[512 + tid];
        float epv = pv * end_w[tid]   + aw * end_w[256 + tid]   + pv * aw * end_w[512 + tid];
        #pragma unroll
        for (int s = 1; s < 64; s <<= 1) {
            spv += __shfl_xor(spv, s);
            epv += __shfl_xor(epv, s);
        }
        if (lane == 0) { redA[wid] = spv; redB[wid] = epv; }
        __syncthreads();                                  // (D) redA/B
        if (tid == 0) {
            int pm = (pass[b * P_ + p] != 0);
            float sv = redA[0] + redA[1] + redA[2] + redA[3] + sb;
            float ev = redB[0] + redB[1] + redB[2] + redB[3] + ebv;
            out[b * P_ + p]       = pm ? sv : NEG;
            out[BP + b * P_ + p]  = pm ? ev : NEG;
        }
        __syncthreads();                                  // (E) end of row
    }
}

// ---------------- log_softmax over P per (batch, start/end) ----------------
__global__ __launch_bounds__(256) void k_lsm(float* out) {
    int b = blockIdx.x >> 1, which = blockIdx.x & 1;
    const float* src = out + which * BP + b * P_;
    int tid = threadIdx.x;
    float v0 = src[tid], v1 = src[tid + 256];
    __shared__ float red[4];
    float m = fmaxf(v0, v1);
    #pragma unroll
    for (int s = 1; s < 64; s <<= 1) m = fmaxf(m, __shfl_xor(m, s));
    if ((tid & 63) == 0) red[tid >> 6] = m;
    __syncthreads();
    m = fmaxf(fmaxf(red[0], red[1]), fmaxf(red[2], red[3]));
    __syncthreads();
    float ss = __expf(v0 - m) + __expf(v1 - m);
    #pragma unroll
    for (int s = 1; s < 64; s <<= 1) ss += __shfl_xor(ss, s);
    if ((tid & 63) == 0) red[tid >> 6] = ss;
    __syncthreads();
    float lse = m + logf(red[0] + red[1] + red[2] + red[3]);
    float* dst = out + (2 + which) * BP + b * P_;
    dst[tid] = v0 - lse;
    dst[tid + 256] = v1 - lse;
}

extern "C" void kernel_launch(void* const* d_in, const int* in_sizes, int n_in,
                              void* d_out, int out_size, void* d_ws, size_t ws_size,
                              hipStream_t stream) {
    const int* pass = (const int*)d_in[0];
    const int* ques = (const int*)d_in[1];
    const float* emb = (const float*)d_in[2];
    PrepArgs pa;
    const float* whh[4];
    const int base[4] = {3, 7, 11, 15};   // p_f, p_b, q_f, q_b blocks of 4 inputs
    for (int i = 0; i < 4; i++) {
        pa.wih[i] = (const float*)d_in[base[i] + 0];
        whh[i]    = (const float*)d_in[base[i] + 1];
        pa.bih[i] = (const float*)d_in[base[i] + 2];
        pa.bhh[i] = (const float*)d_in[base[i] + 3];
    }
    const float* attn_w  = (const float*)d_in[19];
    const float* attn_b  = (const float*)d_in[20];
    const float* start_w = (const float*)d_in[21];
    const float* start_b = (const float*)d_in[22];
    const float* end_w   = (const float*)d_in[23];
    const float* end_b   = (const float*)d_in[24];
    float* out = (float*)d_out;

    k_prepw <<<dim3(1536), dim3(64), 0, stream>>>(pa);
    k_prepw2<<<dim3(4), dim3(128), 0, stream>>>(whh[0], whh[1], whh[2], whh[3]);
    k_gather<<<dim3((BP + BQ) / 4), dim3(256), 0, stream>>>(pass, ques, emb);
    k_gemm  <<<dim3(BP / 128, 6), dim3(256), 0, stream>>>(0);
    k_gemm  <<<dim3(BQ / 128, 6), dim3(256), 0, stream>>>(1);
    k_maskz <<<dim3(BP + BQ), dim3(128), 0, stream>>>(pass, ques);
    k_gru   <<<dim3(128), dim3(128), 0, stream>>>();
    k_attn  <<<dim3(B_ * 64), dim3(256), 0, stream>>>(pass, ques, attn_w, attn_b,
                                                      start_w, start_b, end_w, end_b, out);
    k_lsm   <<<dim3(64), dim3(256), 0, stream>>>(out);
}

// Round 11
// 506.392 us; speedup vs baseline: 1.9905x; 1.1093x over previous
//
#include <hip/hip_runtime.h>
#include <hip/hip_bf16.h>

#define B_ 32
#define P_ 512
#define Q_ 64
#define E_ 300
#define KP 320          // E padded to multiple of 32 for MFMA K-steps
#define H_ 256
#define HH_ 128
#define NEG (-1e7f)
#define BP (B_*P_)
#define BQ (B_*Q_)

typedef __attribute__((ext_vector_type(8))) short bf16x8;
typedef __attribute__((ext_vector_type(4))) float f32x4;
typedef _Float16 half2v __attribute__((ext_vector_type(2)));
typedef unsigned int u32;

// ---- static device workspace (fully rewritten every call) ----
// Embeddings gathered T-MAJOR: row = t*32 + b
__device__ __hip_bfloat16 g_ep[BP][KP];
__device__ __hip_bfloat16 g_eq[BQ][KP];
__device__ __hip_bfloat16 g_wp[768][KP];     // combined passage wih
__device__ __hip_bfloat16 g_wq[768][KP];     // combined question wih
__device__ float g_biasp[768];               // bih (+ bhh for r,z gates)
__device__ float g_biasq[768];
__device__ float g_biasn[4][HH_];            // bhh n-gate bias per weight set
__device__ uint4 g_whhw[4*512*12];           // [widx][tid=(j,q)][gate][4] f16-packed
__device__ float g_xtp[2L*P_*B_*384];        // passage x-proj, [dir][t][b][384] f32
__device__ float g_xtq[2L*Q_*B_*384];        // question x-proj
__device__ float g_penc[BP*H_];              // BiGRU passage encodings (f32)
__device__ float g_qenc[BQ*H_];              // BiGRU question encodings

struct PrepArgs { const float* wih[4]; const float* bih[4]; const float* bhh[4]; };

// ---------------- weight repack + bias fold ----------------
__global__ __launch_bounds__(64) void k_prepw(PrepArgs pa) {
    int r = blockIdx.x;                 // 0..1535
    int pq = r / 768, col = r % 768;
    int dir = col / 384, within = col % 384, gate = within / 128;
    int idx = pq * 2 + dir;             // {p_f,p_b,q_f,q_b}
    const float* wsrc = pa.wih[idx] + within * E_;
    __hip_bfloat16* dst = pq ? g_wq[col] : g_wp[col];
    for (int c = threadIdx.x; c < KP; c += 64)
        dst[c] = __float2bfloat16(c < E_ ? wsrc[c] : 0.f);
    if (threadIdx.x == 0) {
        float bsum = pa.bih[idx][within] + (gate < 2 ? pa.bhh[idx][within] : 0.f);
        (pq ? g_biasq : g_biasp)[col] = bsum;
        if (within >= 256) g_biasn[idx][within - 256] = pa.bhh[idx][within];
    }
}

// ---------------- whh -> per-thread f16-packed quarter-rows ----------------
// thread tid=(j=tid>>2, q=tid&3) owns k-range [q*32, q*32+32) of rows
// {r,z,n gate} x col j: 12 uint4, contiguous per tid for coalescing.
__global__ __launch_bounds__(512) void k_prepw2(const float* w0, const float* w1,
                                               const float* w2, const float* w3) {
    int widx = blockIdx.x;              // 0..3
    const float* whh = widx == 0 ? w0 : widx == 1 ? w1 : widx == 2 ? w2 : w3;
    int tid = threadIdx.x;              // 0..511
    int j = tid >> 2, q = tid & 3;
    uint4* dst = g_whhw + ((long)widx * 512 + tid) * 12;
    for (int g = 0; g < 3; g++)
        for (int i = 0; i < 4; i++) {
            const float* src = whh + (long)(g * 128 + j) * HH_ + q * 32 + i * 8;
            u32 p[4];
            #pragma unroll
            for (int e = 0; e < 4; e++) {
                half2v hp;
                hp[0] = (_Float16)src[2 * e];
                hp[1] = (_Float16)src[2 * e + 1];
                p[e] = __builtin_bit_cast(u32, hp);
            }
            dst[g * 4 + i] = make_uint4(p[0], p[1], p[2], p[3]);
        }
}

// ---------------- embedding gather (T-MAJOR rows, f32 -> bf16) ----------------
__global__ __launch_bounds__(256) void k_gather(const int* pass, const int* ques, const float* emb) {
    int row = blockIdx.x * 4 + (threadIdx.x >> 6);
    int lane = threadIdx.x & 63;
    const int* tsrc; __hip_bfloat16* dst; int r, T;
    if (row < BP) { r = row; tsrc = pass; dst = &g_ep[r][0]; T = P_; }
    else          { r = row - BP; tsrc = ques; dst = &g_eq[r][0]; T = Q_; }
    int b = r & 31, t = r >> 5;         // t-major
    int tk = tsrc[b * T + t];
    const float* src = emb + (long)tk * E_;
    #pragma unroll
    for (int i = 0; i < 5; i++) {
        int c = i * 64 + lane;
        float v = (c < E_) ? src[c] : 0.f;
        dst[c] = __float2bfloat16(v);
    }
}

// ---------------- input-projection GEMM -> f32 [dir][t][b][384] ----------------
__global__ __launch_bounds__(256) void k_gemm(int isQ) {
    const __hip_bfloat16* A  = isQ ? &g_eq[0][0] : &g_ep[0][0];
    const __hip_bfloat16* Bw = isQ ? &g_wq[0][0] : &g_wp[0][0];
    const float* bias = isQ ? g_biasq : g_biasp;
    float* Xt = isQ ? g_xtq : g_xtp;
    const int T = isQ ? Q_ : P_;
    __shared__ __hip_bfloat16 As[128][40];
    __shared__ __hip_bfloat16 Bs[128][40];
    int m0 = blockIdx.x * 128, n0 = blockIdx.y * 128;
    int tid = threadIdx.x, lane = tid & 63, w = tid >> 6;
    int wm = (w & 1) * 64, wn = (w >> 1) * 64;
    f32x4 acc[4][4] = {};
    int lr = tid >> 1, lc = (tid & 1) * 16;
    for (int kt = 0; kt < KP; kt += 32) {
        *(bf16x8*)&As[lr][lc]   = *(const bf16x8*)&A [(m0 + lr) * KP + kt + lc];
        *(bf16x8*)&As[lr][lc+8] = *(const bf16x8*)&A [(m0 + lr) * KP + kt + lc + 8];
        *(bf16x8*)&Bs[lr][lc]   = *(const bf16x8*)&Bw[(n0 + lr) * KP + kt + lc];
        *(bf16x8*)&Bs[lr][lc+8] = *(const bf16x8*)&Bw[(n0 + lr) * KP + kt + lc + 8];
        __syncthreads();
        int kb = (lane >> 4) * 8, l15 = lane & 15;
        bf16x8 af[4], bfr[4];
        #pragma unroll
        for (int i = 0; i < 4; i++) af[i]  = *(bf16x8*)&As[wm + i*16 + l15][kb];
        #pragma unroll
        for (int j = 0; j < 4; j++) bfr[j] = *(bf16x8*)&Bs[wn + j*16 + l15][kb];
        #pragma unroll
        for (int i = 0; i < 4; i++)
            #pragma unroll
            for (int j = 0; j < 4; j++)
                acc[i][j] = __builtin_amdgcn_mfma_f32_16x16x32_bf16(af[i], bfr[j], acc[i][j], 0, 0, 0);
        __syncthreads();
    }
    int l15 = lane & 15, lr4 = (lane >> 4) * 4;
    #pragma unroll
    for (int jj = 0; jj < 4; jj++) {
        int n = n0 + wn + jj * 16 + l15;
        float bn = bias[n];
        int dirn = n >= 384;
        int col = n - dirn * 384;
        float* Cx = Xt + (long)dirn * T * B_ * 384;
        #pragma unroll
        for (int i = 0; i < 4; i++) {
            int mb = m0 + wm + i * 16 + lr4;     // T-major rows: t = m>>5, b = m&31
            int t = mb >> 5, bb = mb & 31;
            #pragma unroll
            for (int q = 0; q < 4; q++)
                Cx[((long)t * B_ + bb + q) * 384 + col] = acc[i][jj][q] + bn;
        }
    }
}

// ---------------- z-gate poison for masked steps (freeze h exactly) ----------------
__global__ __launch_bounds__(128) void k_maskz(const int* pass, const int* ques) {
    int row = blockIdx.x;
    int tid = threadIdx.x;
    int isQ = row >= BP;
    int rr = isQ ? row - BP : row;
    int T = isQ ? Q_ : P_;
    int b = rr / T, t = rr % T;
    int tkn = isQ ? ques[rr] : pass[rr];
    if (tkn != 0) return;
    float* xt = isQ ? g_xtq : g_xtp;
    xt[((long)0 * T * B_ + (long)t * B_ + b) * 384 + 128 + tid] = 1e9f;
    xt[((long)1 * T * B_ + (long)t * B_ + b) * 384 + 128 + tid] = 1e9f;
}

// ---------------- GRU recurrence: 4-way K-split, 512 threads/chain ----------------
// 128 blocks (one per chain) x 512 threads (8 waves -> 2/SIMD for TLP latency
// hiding). Thread (j,q) computes the q-quarter of all 3 gate dots for col j
// (48 dot2, 12 resident uint4 weights), quad-reduces via shfl_xor (DPP, no
// LDS), computes gates redundantly; q==0 lane writes h (2B) + output (4B).
// h exchange: 4 uniform ds_read_b128 / thread, dbuf, one lgkm barrier/step.
#define D1(A, WU, HU) A = __builtin_amdgcn_fdot2( \
    __builtin_bit_cast(half2v, (WU)), __builtin_bit_cast(half2v, (HU)), A, false);
#define D4(A, W, H) D1(A,(W).x,(H).x) D1(A,(W).y,(H).y) D1(A,(W).z,(H).z) D1(A,(W).w,(H).w)

__global__ __launch_bounds__(512, 1) void k_gru() {
    int blk = blockIdx.x;               // [isQ][dir][b]
    int isQ = blk >> 6, loc = blk & 63, dir = loc >> 5, b = loc & 31;
    const int T = isQ ? Q_ : P_;
    const float* xt = (isQ ? g_xtq : g_xtp) + (long)dir * T * B_ * 384;
    float* outp = isQ ? g_qenc : g_penc;
    int widx = isQ * 2 + dir;
    int tid = threadIdx.x;
    int j = tid >> 2, q = tid & 3;      // col 0..127, k-quarter 0..3
    const uint4* wp = g_whhw + ((long)widx * 512 + tid) * 12;
    uint4 w00 = wp[0], w01 = wp[1], w02 = wp[2],  w03 = wp[3];
    uint4 w10 = wp[4], w11 = wp[5], w12 = wp[6],  w13 = wp[7];
    uint4 w20 = wp[8], w21 = wp[9], w22 = wp[10], w23 = wp[11];
    float bnn = g_biasn[widx][j];
    __shared__ uint hbuf[2][64];        // h as packed f16 (256B), double-buffered
    int t0 = dir ? T - 1 : 0;
    int sdt = dir ? -(B_ * 384) : (B_ * 384);
    int sdo = dir ? -H_ : H_;
    int off = (t0 * B_ + b) * 384 + j;
    int ooff = (b * T + t0) * H_ + dir * HH_ + j;
    float xr = xt[off], xz = xt[off + 128], xn = xt[off + 256];
    uint4 z4 = {0u, 0u, 0u, 0u};
    uint4 h0 = z4, h1 = z4, h2 = z4, h3 = z4;
    float hold = 0.f;
    for (int st = 0; st < T; st++) {
        int offn = off + ((st + 1 < T) ? sdt : 0);
        float nxr = xt[offn], nxz = xt[offn + 128], nxn = xt[offn + 256];
        float ar0 = 0.f, ar1 = 0.f, az0 = 0.f, az1 = 0.f, an0 = 0.f, an1 = 0.f;
        D4(ar0, w00, h0) D4(ar1, w01, h1) D4(ar0, w02, h2) D4(ar1, w03, h3)
        D4(az0, w10, h0) D4(az1, w11, h1) D4(az0, w12, h2) D4(az1, w13, h3)
        D4(an0, w20, h0) D4(an1, w21, h1) D4(an0, w22, h2) D4(an1, w23, h3)
        // quad reduce over k-quarters (lanes q^1, q^2 — same col j)
        float ar = ar0 + ar1, az = az0 + az1, an = an0 + an1;
        ar += __shfl_xor(ar, 1); ar += __shfl_xor(ar, 2);
        az += __shfl_xor(az, 1); az += __shfl_xor(az, 2);
        an += __shfl_xor(an, 1); an += __shfl_xor(an, 2);
        // gates (masked steps: xz=1e9 -> z=1 -> h frozen exactly)
        float rg = __builtin_amdgcn_rcpf(1.f + __expf(-(ar + xr)));
        float zg = __builtin_amdgcn_rcpf(1.f + __expf(-(az + xz)));
        float ta = __builtin_amdgcn_fmed3f(fmaf(rg, an + bnn, xn), -15.f, 15.f);
        float e2 = __expf(2.f * ta);
        float th = fmaf(-2.f, __builtin_amdgcn_rcpf(e2 + 1.f), 1.f);
        float hv = fmaf(zg, hold - th, th);
        hold = hv;
        if (q == 0) {
            outp[ooff] = hv;                             // fire-and-forget store
            ((_Float16*)hbuf[st & 1])[j] = (_Float16)hv; // 2B h write
        }
        asm volatile("s_waitcnt lgkmcnt(0)\n\ts_barrier" ::: "memory");
        const uint4* hb = (const uint4*)hbuf[st & 1] + q * 4;
        h0 = hb[0]; h1 = hb[1]; h2 = hb[2]; h3 = hb[3];
        off = offn; ooff += sdo;
        xr = nxr; xz = nxz; xn = nxn;
    }
}

// ---------------- fused attention + output heads ----------------
#define QPAD 260
__global__ __launch_bounds__(256) void k_attn(const int* pass, const int* ques,
        const float* attn_w, const float* attn_b, const float* start_w,
        const float* start_b, const float* end_w, const float* end_b, float* out) {
    __shared__ float qs[Q_][QPAD];
    __shared__ float pw3[H_];
    __shared__ float lrow[Q_];
    __shared__ float probs[Q_];
    __shared__ float s2v[Q_];
    __shared__ int   qmS[Q_];
    __shared__ float red[4], redA[4], redB[4];
    __shared__ float awpart[4][QPAD];
    int b = blockIdx.x >> 6, pch = blockIdx.x & 63;
    int tid = threadIdx.x, lane = tid & 63, wid = tid >> 6;
    for (int i = tid; i < Q_ * H_; i += 256) {
        int q = i >> 8, h = i & 255;
        qs[q][h] = g_qenc[(long)(b * Q_ + q) * H_ + h];
    }
    if (tid < Q_) qmS[tid] = (ques[b * Q_ + tid] != 0);
    __syncthreads();
    int q4 = tid >> 2, part = tid & 3;
    {   // s2[q] = dot(qenc[q], w2)
        float p2 = 0.f;
        #pragma unroll 8
        for (int i = 0; i < 64; i++)
            p2 += qs[q4][part * 64 + i] * attn_w[256 + part * 64 + i];
        p2 += __shfl_xor(p2, 1);
        p2 += __shfl_xor(p2, 2);
        if (part == 0) s2v[q4] = p2;
    }
    __syncthreads();
    float ab = attn_b[0], sb = start_b[0], ebv = end_b[0];
    for (int pi = 0; pi < 8; pi++) {
        int p = pch * 8 + pi;
        float pv = g_penc[(long)(b * P_ + p) * H_ + tid];
        pw3[tid] = pv * attn_w[512 + tid];
        float r1 = pv * attn_w[tid];
        #pragma unroll
        for (int s = 1; s < 64; s <<= 1) r1 += __shfl_xor(r1, s);
        if (lane == 0) red[wid] = r1;
        __syncthreads();                                  // (A) pw3 + red
        float s1 = red[0] + red[1] + red[2] + red[3];
        float acc = 0.f;
        #pragma unroll
        for (int i = 0; i < 16; i++) {
            float4 qv = *(const float4*)&qs[q4][part * 64 + i * 4];
            float4 wv = *(const float4*)&pw3[part * 64 + i * 4];
            acc += qv.x * wv.x + qv.y * wv.y + qv.z * wv.z + qv.w * wv.w;
        }
        acc += __shfl_xor(acc, 1);
        acc += __shfl_xor(acc, 2);
        if (part == 0) lrow[q4] = qmS[q4] ? (s1 + s2v[q4] + acc + ab) : NEG;
        __syncthreads();                                  // (B) lrow
        if (tid < 64) {
            float v = lrow[tid];
            float m = v;
            #pragma unroll
            for (int s = 1; s < 64; s <<= 1) m = fmaxf(m, __shfl_xor(m, s));
            float e = __expf(v - m);
            float ss = e;
            #pragma unroll
            for (int s = 1; s < 64; s <<= 1) ss += __shfl_xor(ss, s);
            probs[tid] = e / ss;
        }
        __syncthreads();                                  // (C) probs
        float4 aw4 = {0.f, 0.f, 0.f, 0.f};
        #pragma unroll
        for (int qq = 0; qq < 16; qq++) {
            int q = wid * 16 + qq;
            float pq = probs[q];
            float4 qv = *(const float4*)&qs[q][lane * 4];
            aw4.x = fmaf(pq, qv.x, aw4.x);
            aw4.y = fmaf(pq, qv.y, aw4.y);
            aw4.z = fmaf(pq, qv.z, aw4.z);
            aw4.w = fmaf(pq, qv.w, aw4.w);
        }
        *(float4*)&awpart[wid][lane * 4] = aw4;
        __syncthreads();                                  // (D0) awpart
        float aw = awpart[0][tid] + awpart[1][tid] + awpart[2][tid] + awpart[3][tid];
        float spv = pv * start_w[tid] + aw * start_w[256 + tid] + pv * aw * start_w[512 + tid];
        float epv = pv * end_w[tid]   + aw * end_w[256 + tid]   + pv * aw * end_w[512 + tid];
        #pragma unroll
        for (int s = 1; s < 64; s <<= 1) {
            spv += __shfl_xor(spv, s);
            epv += __shfl_xor(epv, s);
        }
        if (lane == 0) { redA[wid] = spv; redB[wid] = epv; }
        __syncthreads();                                  // (D) redA/B
        if (tid == 0) {
            int pm = (pass[b * P_ + p] != 0);
            float sv = redA[0] + redA[1] + redA[2] + redA[3] + sb;
            float ev = redB[0] + redB[1] + redB[2] + redB[3] + ebv;
            out[b * P_ + p]       = pm ? sv : NEG;
            out[BP + b * P_ + p]  = pm ? ev : NEG;
        }
        __syncthreads();                                  // (E) end of row
    }
}

// ---------------- log_softmax over P per (batch, start/end) ----------------
__global__ __launch_bounds__(256) void k_lsm(float* out) {
    int b = blockIdx.x >> 1, which = blockIdx.x & 1;
    const float* src = out + which * BP + b * P_;
    int tid = threadIdx.x;
    float v0 = src[tid], v1 = src[tid + 256];
    __shared__ float red[4];
    float m = fmaxf(v0, v1);
    #pragma unroll
    for (int s = 1; s < 64; s <<= 1) m = fmaxf(m, __shfl_xor(m, s));
    if ((tid & 63) == 0) red[tid >> 6] = m;
    __syncthreads();
    m = fmaxf(fmaxf(red[0], red[1]), fmaxf(red[2], red[3]));
    __syncthreads();
    float ss = __expf(v0 - m) + __expf(v1 - m);
    #pragma unroll
    for (int s = 1; s < 64; s <<= 1) ss += __shfl_xor(ss, s);
    if ((tid & 63) == 0) red[tid >> 6] = ss;
    __syncthreads();
    float lse = m + logf(red[0] + red[1] + red[2] + red[3]);
    float* dst = out + (2 + which) * BP + b * P_;
    dst[tid] = v0 - lse;
    dst[tid + 256] = v1 - lse;
}

extern "C" void kernel_launch(void* const* d_in, const int* in_sizes, int n_in,
                              void* d_out, int out_size, void* d_ws, size_t ws_size,
                              hipStream_t stream) {
    const int* pass = (const int*)d_in[0];
    const int* ques = (const int*)d_in[1];
    const float* emb = (const float*)d_in[2];
    PrepArgs pa;
    const float* whh[4];
    const int base[4] = {3, 7, 11, 15};   // p_f, p_b, q_f, q_b blocks of 4 inputs
    for (int i = 0; i < 4; i++) {
        pa.wih[i] = (const float*)d_in[base[i] + 0];
        whh[i]    = (const float*)d_in[base[i] + 1];
        pa.bih[i] = (const float*)d_in[base[i] + 2];
        pa.bhh[i] = (const float*)d_in[base[i] + 3];
    }
    const float* attn_w  = (const float*)d_in[19];
    const float* attn_b  = (const float*)d_in[20];
    const float* start_w = (const float*)d_in[21];
    const float* start_b = (const float*)d_in[22];
    const float* end_w   = (const float*)d_in[23];
    const float* end_b   = (const float*)d_in[24];
    float* out = (float*)d_out;

    k_prepw <<<dim3(1536), dim3(64), 0, stream>>>(pa);
    k_prepw2<<<dim3(4), dim3(512), 0, stream>>>(whh[0], whh[1], whh[2], whh[3]);
    k_gather<<<dim3((BP + BQ) / 4), dim3(256), 0, stream>>>(pass, ques, emb);
    k_gemm  <<<dim3(BP / 128, 6), dim3(256), 0, stream>>>(0);
    k_gemm  <<<dim3(BQ / 128, 6), dim3(256), 0, stream>>>(1);
    k_maskz <<<dim3(BP + BQ), dim3(128), 0, stream>>>(pass, ques);
    k_gru   <<<dim3(128), dim3(512), 0, stream>>>();
    k_attn  <<<dim3(B_ * 64), dim3(256), 0, stream>>>(pass, ques, attn_w, attn_b,
                                                      start_w, start_b, end_w, end_b, out);
    k_lsm   <<<dim3(64), dim3(256), 0, stream>>>(out);
}